// Round 1
// baseline (404.694 us; speedup 1.0000x reference)
//
#include <hip/hip_runtime.h>
#include <math.h>

// Problem constants (fixed by setup_inputs)
constexpr int Bsz   = 64;
constexpr int Mmel  = 80;
constexpr int Tout  = 2000;
constexpr int Tin   = 400;
constexpr int MEL_N  = Bsz * Mmel * Tout;   // 10,240,000
constexpr int GATE_N = Bsz * Tout;          // 128,000
constexpr int ALN_N  = Bsz * Tout * Tin;    // 51,200,000

constexpr float ATT_W = 0.1f;
constexpr float GA_W  = 0.1f;
constexpr float INV_2SIG2 = 3.125f;         // 1 / (2 * 0.4^2)

constexpr int NBLK = 1024;
constexpr int NTHR = 256;

__device__ __forceinline__ float wave_reduce(float v) {
    #pragma unroll
    for (int off = 32; off > 0; off >>= 1)
        v += __shfl_down(v, off, 64);
    return v;
}

__global__ __launch_bounds__(NTHR) void loss_main(
    const float* __restrict__ mel_out,
    const float* __restrict__ mel_post,
    const float* __restrict__ gate_out,
    const float* __restrict__ align,
    const float* __restrict__ mel_tgt,
    const float* __restrict__ gate_tgt,
    const int*   __restrict__ in_len,
    const int*   __restrict__ out_len,
    double* __restrict__ acc)   // acc[0]=mel_sum acc[1]=gate_sum acc[2]=att_sum acc[3]=ga_sum
{
    const int tid      = blockIdx.x * blockDim.x + threadIdx.x;
    const int nthreads = gridDim.x * blockDim.x;

    float mel_s = 0.f, gate_s = 0.f, att_s = 0.f, ga_s = 0.f;

    // ---- Mel L1 (both decoder and postnet share the denominator) ----
    {
        const float4* a4 = (const float4*)mel_out;
        const float4* p4 = (const float4*)mel_post;
        const float4* t4 = (const float4*)mel_tgt;
        const int n4 = MEL_N / 4;
        for (int i = tid; i < n4; i += nthreads) {
            float4 a = a4[i], p = p4[i], t = t4[i];
            mel_s += fabsf(a.x - t.x) + fabsf(a.y - t.y) + fabsf(a.z - t.z) + fabsf(a.w - t.w);
            mel_s += fabsf(p.x - t.x) + fabsf(p.y - t.y) + fabsf(p.z - t.z) + fabsf(p.w - t.w);
        }
    }

    // ---- Gate BCE-with-logits ----
    {
        const float4* x4 = (const float4*)gate_out;
        const float4* z4 = (const float4*)gate_tgt;
        const int n4 = GATE_N / 4;
        for (int i = tid; i < n4; i += nthreads) {
            float4 x = x4[i], z = z4[i];
            gate_s += fmaxf(x.x, 0.f) - x.x * z.x + log1pf(expf(-fabsf(x.x)));
            gate_s += fmaxf(x.y, 0.f) - x.y * z.y + log1pf(expf(-fabsf(x.y)));
            gate_s += fmaxf(x.z, 0.f) - x.z * z.z + log1pf(expf(-fabsf(x.z)));
            gate_s += fmaxf(x.w, 0.f) - x.w * z.w + log1pf(expf(-fabsf(x.w)));
        }
    }

    // ---- Alignment terms: monotonic-attention penalty + guided attention ----
    {
        const float4* al4 = (const float4*)align;
        const int n4 = ALN_N / 4;               // 12,800,000
        constexpr int TIN4 = Tin / 4;           // 100 float4 per row
        for (int i = tid; i < n4; i += nthreads) {
            float4 a = al4[i];
            const int row  = i / TIN4;          // b * Tout + irow
            const int j0   = (i - row * TIN4) * 4;
            const int irow = row % Tout;
            const int b    = row / Tout;
            const int il   = in_len[b];
            const int ol   = out_len[b];
            const float scale = (float)ol / (float)il;   // T_out_b / T_in_b
            const bool row_valid = irow < ol;
            const float fi = (float)irow;

            const float av[4] = {a.x, a.y, a.z, a.w};
            #pragma unroll
            for (int k = 0; k < 4; ++k) {
                const int jj = j0 + k;
                if (jj < irow) att_s += av[k];
                if (row_valid && jj < il) {
                    const float d = fi - (float)jj * scale;
                    ga_s += av[k] * (1.0f - __expf(-d * d * INV_2SIG2));
                }
            }
        }
    }

    // ---- Block reduction: wave shuffle -> LDS -> one atomic per block ----
    __shared__ float smem[4][4];                 // [wave][accumulator]
    const int lane = threadIdx.x & 63;
    const int wid  = threadIdx.x >> 6;

    mel_s  = wave_reduce(mel_s);
    gate_s = wave_reduce(gate_s);
    att_s  = wave_reduce(att_s);
    ga_s   = wave_reduce(ga_s);
    if (lane == 0) {
        smem[wid][0] = mel_s;
        smem[wid][1] = gate_s;
        smem[wid][2] = att_s;
        smem[wid][3] = ga_s;
    }
    __syncthreads();
    if (threadIdx.x == 0) {
        float m = 0.f, g = 0.f, at = 0.f, ga = 0.f;
        #pragma unroll
        for (int w = 0; w < NTHR / 64; ++w) {
            m  += smem[w][0];
            g  += smem[w][1];
            at += smem[w][2];
            ga += smem[w][3];
        }
        atomicAdd(&acc[0], (double)m);
        atomicAdd(&acc[1], (double)g);
        atomicAdd(&acc[2], (double)at);
        atomicAdd(&acc[3], (double)ga);
    }
}

__global__ void loss_final(const double* __restrict__ acc, float* __restrict__ out) {
    const double mel  = acc[0] / (double)MEL_N;
    const double gate = acc[1] / (double)GATE_N;
    const double att  = acc[2] / (double)Bsz;
    const double ga   = acc[3] / (double)Bsz;
    const double total = mel + gate + (double)ATT_W * att + (double)GA_W * ga;
    out[0] = (float)total;
    out[1] = (float)mel;
    out[2] = (float)gate;
    out[3] = (float)att;
    out[4] = (float)ga;
}

extern "C" void kernel_launch(void* const* d_in, const int* in_sizes, int n_in,
                              void* d_out, int out_size, void* d_ws, size_t ws_size,
                              hipStream_t stream) {
    const float* mel_out  = (const float*)d_in[0];
    const float* mel_post = (const float*)d_in[1];
    const float* gate_out = (const float*)d_in[2];
    const float* align    = (const float*)d_in[3];
    const float* mel_tgt  = (const float*)d_in[4];
    const float* gate_tgt = (const float*)d_in[5];
    const int*   in_len   = (const int*)d_in[6];
    const int*   out_len  = (const int*)d_in[7];

    double* acc = (double*)d_ws;
    hipMemsetAsync(acc, 0, 4 * sizeof(double), stream);

    loss_main<<<NBLK, NTHR, 0, stream>>>(mel_out, mel_post, gate_out, align,
                                         mel_tgt, gate_tgt, in_len, out_len, acc);
    loss_final<<<1, 1, 0, stream>>>(acc, (float*)d_out);
}

// Round 2
// 372.748 us; speedup vs baseline: 1.0857x; 1.0857x over previous
//
#include <hip/hip_runtime.h>
#include <math.h>

// Problem constants (fixed by setup_inputs)
constexpr int Bsz   = 64;
constexpr int Mmel  = 80;
constexpr int Tout  = 2000;
constexpr int Tin   = 400;
constexpr int MEL_N  = Bsz * Mmel * Tout;   // 10,240,000
constexpr int GATE_N = Bsz * Tout;          // 128,000
constexpr int ALN_N  = Bsz * Tout * Tin;    // 51,200,000
constexpr int TIN4   = Tin / 4;             // 100

constexpr float ATT_W = 0.1f;
constexpr float GA_W  = 0.1f;
constexpr float INV_2SIG2 = 3.125f;         // 1 / (2 * 0.4^2)

constexpr int NBLK = 6144;                  // 24 blocks/CU queued; VGPR=28 -> full residency
constexpr int NTHR = 256;

__device__ __forceinline__ float wave_reduce(float v) {
    #pragma unroll
    for (int off = 32; off > 0; off >>= 1)
        v += __shfl_down(v, off, 64);
    return v;
}

__device__ __forceinline__ double wave_reduce_d(double v) {
    #pragma unroll
    for (int off = 32; off > 0; off >>= 1)
        v += __shfl_down(v, off, 64);
    return v;
}

__device__ __forceinline__ void process_aln(
    float4 a, int i,
    const int* __restrict__ s_il, const int* __restrict__ s_ol,
    const float* __restrict__ s_scale,
    float& att_s, float& ga_s)
{
    const int row  = i / TIN4;              // b * Tout + irow (magic-mul)
    const int j0   = (i - row * TIN4) * 4;
    const int irow = row % Tout;
    const int b    = row / Tout;
    const int il   = s_il[b];               // LDS broadcast (free)
    const int ol   = s_ol[b];
    const float scale = s_scale[b];
    const bool row_valid = irow < ol;
    const float fi = (float)irow;

    const float av[4] = {a.x, a.y, a.z, a.w};
    #pragma unroll
    for (int k = 0; k < 4; ++k) {
        const int jj = j0 + k;
        att_s += (jj < irow) ? av[k] : 0.0f;
        const float d = fi - (float)jj * scale;
        const float w = 1.0f - __expf(-d * d * INV_2SIG2);
        ga_s += (row_valid && jj < il) ? av[k] * w : 0.0f;
    }
}

__global__ __launch_bounds__(NTHR) void loss_main(
    const float* __restrict__ mel_out,
    const float* __restrict__ mel_post,
    const float* __restrict__ gate_out,
    const float* __restrict__ align,
    const float* __restrict__ mel_tgt,
    const float* __restrict__ gate_tgt,
    const int*   __restrict__ in_len,
    const int*   __restrict__ out_len,
    float4* __restrict__ partials)          // partials[blockIdx] = {mel, gate, att, ga}
{
    __shared__ int   s_il[Bsz];
    __shared__ int   s_ol[Bsz];
    __shared__ float s_scale[Bsz];
    if (threadIdx.x < Bsz) {
        const int il = in_len[threadIdx.x];
        const int ol = out_len[threadIdx.x];
        s_il[threadIdx.x] = il;
        s_ol[threadIdx.x] = ol;
        s_scale[threadIdx.x] = (float)ol / (float)il;
    }
    __syncthreads();

    const int tid    = blockIdx.x * blockDim.x + threadIdx.x;
    const int stride = gridDim.x * blockDim.x;

    float mel_s = 0.f, gate_s = 0.f, att_s = 0.f, ga_s = 0.f;

    // ---- Mel L1 (decoder + postnet), unroll x2 for MLP ----
    {
        const float4* a4 = (const float4*)mel_out;
        const float4* p4 = (const float4*)mel_post;
        const float4* t4 = (const float4*)mel_tgt;
        const int n4 = MEL_N / 4;
        int i = tid;
        for (; i + stride < n4; i += 2 * stride) {
            const int i1 = i + stride;
            float4 a0 = a4[i],  a1 = a4[i1];
            float4 p0 = p4[i],  p1 = p4[i1];
            float4 t0 = t4[i],  t1 = t4[i1];
            mel_s += fabsf(a0.x - t0.x) + fabsf(a0.y - t0.y) + fabsf(a0.z - t0.z) + fabsf(a0.w - t0.w);
            mel_s += fabsf(p0.x - t0.x) + fabsf(p0.y - t0.y) + fabsf(p0.z - t0.z) + fabsf(p0.w - t0.w);
            mel_s += fabsf(a1.x - t1.x) + fabsf(a1.y - t1.y) + fabsf(a1.z - t1.z) + fabsf(a1.w - t1.w);
            mel_s += fabsf(p1.x - t1.x) + fabsf(p1.y - t1.y) + fabsf(p1.z - t1.z) + fabsf(p1.w - t1.w);
        }
        for (; i < n4; i += stride) {
            float4 a = a4[i], p = p4[i], t = t4[i];
            mel_s += fabsf(a.x - t.x) + fabsf(a.y - t.y) + fabsf(a.z - t.z) + fabsf(a.w - t.w);
            mel_s += fabsf(p.x - t.x) + fabsf(p.y - t.y) + fabsf(p.z - t.z) + fabsf(p.w - t.w);
        }
    }

    // ---- Gate BCE-with-logits (tiny) ----
    {
        const float4* x4 = (const float4*)gate_out;
        const float4* z4 = (const float4*)gate_tgt;
        const int n4 = GATE_N / 4;
        for (int i = tid; i < n4; i += stride) {
            float4 x = x4[i], z = z4[i];
            gate_s += fmaxf(x.x, 0.f) - x.x * z.x + log1pf(expf(-fabsf(x.x)));
            gate_s += fmaxf(x.y, 0.f) - x.y * z.y + log1pf(expf(-fabsf(x.y)));
            gate_s += fmaxf(x.z, 0.f) - x.z * z.z + log1pf(expf(-fabsf(x.z)));
            gate_s += fmaxf(x.w, 0.f) - x.w * z.w + log1pf(expf(-fabsf(x.w)));
        }
    }

    // ---- Alignment terms (205 MB, the dominant stream), unroll x4 ----
    {
        const float4* al4 = (const float4*)align;
        const int n4 = ALN_N / 4;               // 12,800,000
        int i = tid;
        for (; i + 3 * stride < n4; i += 4 * stride) {
            // 4 independent loads in flight before any dependent compute
            float4 a0 = al4[i];
            float4 a1 = al4[i + stride];
            float4 a2 = al4[i + 2 * stride];
            float4 a3 = al4[i + 3 * stride];
            process_aln(a0, i,              s_il, s_ol, s_scale, att_s, ga_s);
            process_aln(a1, i + stride,     s_il, s_ol, s_scale, att_s, ga_s);
            process_aln(a2, i + 2 * stride, s_il, s_ol, s_scale, att_s, ga_s);
            process_aln(a3, i + 3 * stride, s_il, s_ol, s_scale, att_s, ga_s);
        }
        for (; i < n4; i += stride)
            process_aln(al4[i], i, s_il, s_ol, s_scale, att_s, ga_s);
    }

    // ---- Block reduction: wave shuffle -> LDS -> one partial write per block ----
    __shared__ float smem[NTHR / 64][4];
    const int lane = threadIdx.x & 63;
    const int wid  = threadIdx.x >> 6;

    mel_s  = wave_reduce(mel_s);
    gate_s = wave_reduce(gate_s);
    att_s  = wave_reduce(att_s);
    ga_s   = wave_reduce(ga_s);
    if (lane == 0) {
        smem[wid][0] = mel_s;
        smem[wid][1] = gate_s;
        smem[wid][2] = att_s;
        smem[wid][3] = ga_s;
    }
    __syncthreads();
    if (threadIdx.x == 0) {
        float m = 0.f, g = 0.f, at = 0.f, ga = 0.f;
        #pragma unroll
        for (int w = 0; w < NTHR / 64; ++w) {
            m  += smem[w][0];
            g  += smem[w][1];
            at += smem[w][2];
            ga += smem[w][3];
        }
        partials[blockIdx.x] = make_float4(m, g, at, ga);
    }
}

__global__ __launch_bounds__(512) void loss_final(
    const float4* __restrict__ partials, float* __restrict__ out)
{
    double m = 0.0, g = 0.0, at = 0.0, ga = 0.0;
    for (int i = threadIdx.x; i < NBLK; i += 512) {
        float4 p = partials[i];
        m += p.x; g += p.y; at += p.z; ga += p.w;
    }
    m  = wave_reduce_d(m);
    g  = wave_reduce_d(g);
    at = wave_reduce_d(at);
    ga = wave_reduce_d(ga);

    __shared__ double smem[8][4];
    const int lane = threadIdx.x & 63;
    const int wid  = threadIdx.x >> 6;
    if (lane == 0) {
        smem[wid][0] = m; smem[wid][1] = g; smem[wid][2] = at; smem[wid][3] = ga;
    }
    __syncthreads();
    if (threadIdx.x == 0) {
        double ms = 0, gs = 0, ats = 0, gas = 0;
        #pragma unroll
        for (int w = 0; w < 8; ++w) {
            ms += smem[w][0]; gs += smem[w][1]; ats += smem[w][2]; gas += smem[w][3];
        }
        const double mel  = ms  / (double)MEL_N;
        const double gate = gs  / (double)GATE_N;
        const double att  = ats / (double)Bsz;
        const double gav  = gas / (double)Bsz;
        const double total = mel + gate + (double)ATT_W * att + (double)GA_W * gav;
        out[0] = (float)total;
        out[1] = (float)mel;
        out[2] = (float)gate;
        out[3] = (float)att;
        out[4] = (float)gav;
    }
}

extern "C" void kernel_launch(void* const* d_in, const int* in_sizes, int n_in,
                              void* d_out, int out_size, void* d_ws, size_t ws_size,
                              hipStream_t stream) {
    const float* mel_out  = (const float*)d_in[0];
    const float* mel_post = (const float*)d_in[1];
    const float* gate_out = (const float*)d_in[2];
    const float* align    = (const float*)d_in[3];
    const float* mel_tgt  = (const float*)d_in[4];
    const float* gate_tgt = (const float*)d_in[5];
    const int*   in_len   = (const int*)d_in[6];
    const int*   out_len  = (const int*)d_in[7];

    float4* partials = (float4*)d_ws;       // NBLK * 16 B = 96 KiB, each block overwrites its slot

    loss_main<<<NBLK, NTHR, 0, stream>>>(mel_out, mel_post, gate_out, align,
                                         mel_tgt, gate_tgt, in_len, out_len, partials);
    loss_final<<<1, 512, 0, stream>>>(partials, (float*)d_out);
}